// Round 9
// baseline (326.421 us; speedup 1.0000x reference)
//
#include <hip/hip_runtime.h>
#include <hip/hip_bf16.h>
#include <hip/hip_fp16.h>

#define D 64
#define RB 128            // rows per bin (7-bit local row)
#define NB_MAX 1024       // max bins (n_nodes <= 2^17)
#define NBLK 256          // blocks for count/scatter passes (must match!)
#define CAP 5120          // K5 LDS staging capacity (records) = 40 KB

typedef unsigned long long ull;

// ---------------- fallback: round-1 atomic kernel ----------------
__global__ __launch_bounds__(256) void spmm_atomic_kernel(
    const float* __restrict__ x,
    const int*   __restrict__ edge_row,
    const int*   __restrict__ edge_col,
    const float* __restrict__ edge_val,
    float*       __restrict__ out,
    int n_edges)
{
    const int gtid = blockIdx.x * blockDim.x + threadIdx.x;
    const int wave = gtid >> 6;
    const int lane = threadIdx.x & 63;
    if (wave >= n_edges) return;
    const int   r = edge_row[wave];
    const int   c = edge_col[wave];
    const float v = edge_val[wave];
    atomicAdd(&out[(size_t)r * D + lane], v * x[(size_t)c * D + lane]);
}

// ---------------- x -> fp16 (halves the gather line count: 1x128B line/row) ----
__global__ void tohalf_kernel(const float* __restrict__ x,
                              __half2* __restrict__ xh2, int n4)
{
    const int i = blockIdx.x * blockDim.x + threadIdx.x;
    if (i < n4) {
        const float4 v = ((const float4*)x)[i];
        xh2[2 * i + 0] = __floats2half2_rn(v.x, v.y);
        xh2[2 * i + 1] = __floats2half2_rn(v.z, v.w);
    }
}

// ---------------- K1: per-block bin counts (LDS hist, coalesced write, NO global atomics) ----
__global__ __launch_bounds__(256) void count_kernel(
    const int* __restrict__ rows, int* __restrict__ counts,
    int n_edges, int nb)
{
    __shared__ int cnt[NB_MAX];
    const int t = threadIdx.x, blk = blockIdx.x;
    for (int i = t; i < nb; i += 256) cnt[i] = 0;
    __syncthreads();
    for (int i = blk * 256 + t; i < n_edges; i += NBLK * 256)
        atomicAdd(&cnt[rows[i] >> 7], 1);          // LDS atomic
    __syncthreads();
    for (int i = t; i < nb; i += 256) counts[blk * nb + i] = cnt[i];
}

// ---------------- K2: per-bin exclusive scan over the NBLK blocks ----------------
// counts[blk][bin] -> cursorbase (in place, exclusive within bin); binsum[bin]
__global__ __launch_bounds__(NBLK) void scan_blocks_kernel(
    int* __restrict__ counts, int* __restrict__ binsum, int nb)
{
    __shared__ int s[NBLK];
    const int b = blockIdx.x, t = threadIdx.x;
    const int mine = counts[t * nb + b];
    s[t] = mine;
    for (int off = 1; off < NBLK; off <<= 1) {
        __syncthreads();
        int v = (t >= off) ? s[t - off] : 0;
        __syncthreads();
        s[t] += v;
    }
    counts[t * nb + b] = s[t] - mine;       // exclusive within bin
    if (t == NBLK - 1) binsum[b] = s[t];
}

// ---------------- K3: exclusive scan over bins -> binbase[nb+1] ----------------
__global__ __launch_bounds__(1024) void scan_bins_kernel(
    const int* __restrict__ binsum, int* __restrict__ binbase, int nb)
{
    __shared__ int s[1024];
    const int t = threadIdx.x;
    const int mine = (t < nb) ? binsum[t] : 0;
    s[t] = mine;
    for (int off = 1; off < 1024; off <<= 1) {
        __syncthreads();
        int v = (t >= off) ? s[t - off] : 0;
        __syncthreads();
        s[t] += v;
    }
    if (t < nb) binbase[t] = s[t] - mine;
    if (t == nb - 1) binbase[nb] = s[t];
}

// ---------------- K4: scatter into PRIVATE per-(block,bin) ranges ----------------
// Same grid/blockDim/loop as K1 -> identical edge assignment -> counts match.
// rec = [ val:f32 (hi32) | localrow:bits17-23 | col:bits0-16 (lo32) ]
// No global atomics; each range has a single writer -> L2 merges the 8B stores.
__global__ __launch_bounds__(256) void scatter_kernel(
    const int* __restrict__ rows, const int* __restrict__ cols,
    const float* __restrict__ vals,
    const int* __restrict__ cursorbase, const int* __restrict__ binbase,
    ull* __restrict__ recs, int n_edges, int nb)
{
    __shared__ int cur[NB_MAX];
    const int t = threadIdx.x, blk = blockIdx.x;
    for (int i = t; i < nb; i += 256)
        cur[i] = binbase[i] + cursorbase[blk * nb + i];
    __syncthreads();
    for (int i = blk * 256 + t; i < n_edges; i += NBLK * 256) {
        const int r = rows[i];
        const unsigned lo = ((unsigned)(r & (RB - 1)) << 17) | (unsigned)cols[i];
        const int pos = atomicAdd(&cur[r >> 7], 1);   // LDS atomic
        recs[pos] = ((ull)__float_as_uint(vals[i]) << 32) | (ull)lo;
    }
}

// ---------------- K5: in-place per-bin sort to exact row order + row offsets ----------------
__global__ __launch_bounds__(256) void binsort_kernel(
    ull* __restrict__ recs, const int* __restrict__ binbase,
    int* __restrict__ offsets_row, int* __restrict__ flags,
    int nb, int n_nodes)
{
    __shared__ ull stage[CAP];
    __shared__ int cnt[RB], sc[RB], cur[RB];
    const int b = blockIdx.x, t = threadIdx.x;
    const int s0 = binbase[b], s1 = binbase[b + 1], len = s1 - s0;

    if (len > CAP) { if (t == 0) flags[b] = 1; return; }   // uniform-block early exit

    for (int i = t; i < RB; i += 256) cnt[i] = 0;
    __syncthreads();

    // stage + local row histogram
    for (int i = t; i < len; i += 256) {
        const ull rr = recs[s0 + i];
        stage[i] = rr;
        atomicAdd(&cnt[(int)((rr >> 17) & (RB - 1))], 1);
    }
    __syncthreads();

    // inclusive scan of cnt[128] (all 256 threads hit barriers)
    if (t < RB) sc[t] = cnt[t];
    for (int off = 1; off < RB; off <<= 1) {
        __syncthreads();
        int v = (t < RB && t >= off) ? sc[t - off] : 0;
        __syncthreads();
        if (t < RB) sc[t] += v;
    }
    __syncthreads();

    if (t < RB) cur[t] = sc[t] - cnt[t];                   // exclusive
    // emit global row offsets (entry RB duplicates next bin's base — same value)
    if (t <= RB) {
        const int r = b * RB + t;
        if (r <= n_nodes)
            offsets_row[r] = s0 + ((t == RB) ? len : (sc[t] - cnt[t]));
    }
    __syncthreads();

    // permute in place (writes stay inside this block's 33 KB segment -> L2-local)
    for (int i = t; i < len; i += 256) {
        const ull rr = stage[i];
        const int p = atomicAdd(&cur[(int)((rr >> 17) & (RB - 1))], 1);
        recs[s0 + p] = rr;
    }
}

// ---------------- K6a: CSR SpMM fp16-x, one wave per row, lane = feature ----------------
__global__ __launch_bounds__(256) void spmm_csr_half_kernel(
    const __half* __restrict__ xh,
    const int*   __restrict__ offsets_row,
    const int*   __restrict__ binbase,
    const ull*   __restrict__ recs,
    const int*   __restrict__ flags,
    float*       __restrict__ out,
    int n_nodes)
{
    const int row  = blockIdx.x * 4 + (threadIdx.x >> 6);
    const int lane = threadIdx.x & 63;
    if (row >= n_nodes) return;

    float acc = 0.f;
    const int b = row >> 7;

    if (__builtin_expect(flags[b], 0)) {
        const int s  = binbase[b];
        const int e  = binbase[b + 1];
        const int lr = row & (RB - 1);
        for (int j = s; j < e; ++j) {
            const ull rec = recs[j];
            if ((int)((rec >> 17) & (RB - 1)) == lr) {
                const int   c = (int)((unsigned)rec & 0x1FFFF);
                const float v = __uint_as_float((unsigned)(rec >> 32));
                acc += v * __half2float(xh[(size_t)c * D + lane]);
            }
        }
    } else {
        const int s = offsets_row[row];
        const int e = offsets_row[row + 1];
        int j = s;
        for (; j + 8 <= e; j += 8) {
            float vv[8], xv[8];
            #pragma unroll
            for (int k = 0; k < 8; ++k) {
                const ull rec = recs[j + k];
                vv[k] = __uint_as_float((unsigned)(rec >> 32));
                const int c = (int)((unsigned)rec & 0x1FFFF);
                xv[k] = __half2float(xh[(size_t)c * D + lane]);
            }
            #pragma unroll
            for (int k = 0; k < 8; ++k) acc += vv[k] * xv[k];
        }
        for (; j < e; ++j) {
            const ull rec = recs[j];
            const float v = __uint_as_float((unsigned)(rec >> 32));
            const int   c = (int)((unsigned)rec & 0x1FFFF);
            acc += v * __half2float(xh[(size_t)c * D + lane]);
        }
    }
    out[(size_t)row * D + lane] = acc;
}

// ---------------- K6b: CSR SpMM fp32-x (used only if ws can't fit xh) ----------------
__global__ __launch_bounds__(256) void spmm_csr_kernel(
    const float* __restrict__ x,
    const int*   __restrict__ offsets_row,
    const int*   __restrict__ binbase,
    const ull*   __restrict__ recs,
    const int*   __restrict__ flags,
    float*       __restrict__ out,
    int n_nodes)
{
    const int row  = blockIdx.x * 4 + (threadIdx.x >> 6);
    const int lane = threadIdx.x & 63;
    if (row >= n_nodes) return;

    float acc = 0.f;
    const int b = row >> 7;

    if (__builtin_expect(flags[b], 0)) {
        const int s  = binbase[b];
        const int e  = binbase[b + 1];
        const int lr = row & (RB - 1);
        for (int j = s; j < e; ++j) {
            const ull rec = recs[j];
            if ((int)((rec >> 17) & (RB - 1)) == lr) {
                const int   c = (int)((unsigned)rec & 0x1FFFF);
                const float v = __uint_as_float((unsigned)(rec >> 32));
                acc += v * x[(size_t)c * D + lane];
            }
        }
    } else {
        const int s = offsets_row[row];
        const int e = offsets_row[row + 1];
        int j = s;
        for (; j + 8 <= e; j += 8) {
            float vv[8], xv[8];
            #pragma unroll
            for (int k = 0; k < 8; ++k) {
                const ull rec = recs[j + k];
                vv[k] = __uint_as_float((unsigned)(rec >> 32));
                const int c = (int)((unsigned)rec & 0x1FFFF);
                xv[k] = x[(size_t)c * D + lane];
            }
            #pragma unroll
            for (int k = 0; k < 8; ++k) acc += vv[k] * xv[k];
        }
        for (; j < e; ++j) {
            const ull rec = recs[j];
            const float v = __uint_as_float((unsigned)(rec >> 32));
            const int   c = (int)((unsigned)rec & 0x1FFFF);
            acc += v * x[(size_t)c * D + lane];
        }
    }
    out[(size_t)row * D + lane] = acc;
}

static inline size_t align16(size_t v) { return (v + 15) & ~(size_t)15; }

extern "C" void kernel_launch(void* const* d_in, const int* in_sizes, int n_in,
                              void* d_out, int out_size, void* d_ws, size_t ws_size,
                              hipStream_t stream)
{
    // setup_inputs order: t, x, edge_row, edge_col, edge_val
    const float* x        = (const float*)d_in[1];
    const int*   edge_row = (const int*)d_in[2];
    const int*   edge_col = (const int*)d_in[3];
    const float* edge_val = (const float*)d_in[4];
    float*       out      = (float*)d_out;

    const int n_edges = in_sizes[2];
    const int n_nodes = out_size / D;
    const int nb      = (n_nodes + RB - 1) / RB;

    // workspace carve (base layout)
    const size_t off_recs    = 0;                                              // n_edges * 8
    const size_t off_counts  = align16(off_recs + (size_t)n_edges * 8);        // NBLK*nb ints
    const size_t off_binsum  = align16(off_counts + (size_t)NBLK * nb * 4);    // nb ints
    const size_t off_binbase = align16(off_binsum + (size_t)nb * 4);           // nb+1 ints
    const size_t off_rowoffs = align16(off_binbase + (size_t)(nb + 1) * 4);    // n_nodes+1 ints
    const size_t off_flags   = align16(off_rowoffs + (size_t)(n_nodes + 1) * 4); // nb ints
    const size_t base_needed = off_flags + (size_t)nb * 4;
    // optional fp16 copy of x
    const size_t off_xhalf   = align16(base_needed);                           // n_nodes*D*2 bytes
    const size_t half_needed = off_xhalf + (size_t)n_nodes * D * 2;
    const bool   use_half    = (ws_size >= half_needed);

    if (ws_size < base_needed || nb > NB_MAX || n_nodes > (1 << 17)) {
        hipMemsetAsync(out, 0, (size_t)out_size * sizeof(float), stream);
        const int n_blocks = (n_edges + 3) / 4;
        spmm_atomic_kernel<<<n_blocks, 256, 0, stream>>>(
            x, edge_row, edge_col, edge_val, out, n_edges);
        return;
    }

    char* ws = (char*)d_ws;
    ull*    recs        = (ull*)(ws + off_recs);
    int*    counts      = (int*)(ws + off_counts);   // becomes cursorbase after K2
    int*    binsum      = (int*)(ws + off_binsum);
    int*    binbase     = (int*)(ws + off_binbase);
    int*    offsets_row = (int*)(ws + off_rowoffs);
    int*    flags       = (int*)(ws + off_flags);
    __half* xh          = (__half*)(ws + off_xhalf);

    hipMemsetAsync(flags, 0, (size_t)nb * sizeof(int), stream);

    // K0: fp16 copy of x (runs while nothing depends on it until K6)
    if (use_half) {
        const int n4 = (n_nodes * D) / 4;   // D=64 -> divisible by 4
        tohalf_kernel<<<(n4 + 255) / 256, 256, 0, stream>>>(x, (__half2*)xh, n4);
    }

    // K1: per-block bin counts
    count_kernel<<<NBLK, 256, 0, stream>>>(edge_row, counts, n_edges, nb);
    // K2: per-bin scan over blocks -> private ranges
    scan_blocks_kernel<<<nb, NBLK, 0, stream>>>(counts, binsum, nb);
    // K3: bin bases
    scan_bins_kernel<<<1, 1024, 0, stream>>>(binsum, binbase, nb);
    // K4: atomic-free scatter into private contiguous ranges
    scatter_kernel<<<NBLK, 256, 0, stream>>>(edge_row, edge_col, edge_val,
                                             counts, binbase, recs, n_edges, nb);
    // K5: per-bin LDS sort to exact row order + row offsets
    binsort_kernel<<<nb, 256, 0, stream>>>(recs, binbase, offsets_row, flags,
                                           nb, n_nodes);
    // K6: CSR SpMM, one wave per row (fp16 gather: one 128B line per edge)
    if (use_half)
        spmm_csr_half_kernel<<<(n_nodes + 3) / 4, 256, 0, stream>>>(
            xh, offsets_row, binbase, recs, flags, out, n_nodes);
    else
        spmm_csr_kernel<<<(n_nodes + 3) / 4, 256, 0, stream>>>(
            x, offsets_row, binbase, recs, flags, out, n_nodes);
}

// Round 10
// 306.981 us; speedup vs baseline: 1.0633x; 1.0633x over previous
//
#include <hip/hip_runtime.h>
#include <hip/hip_bf16.h>
#include <hip/hip_fp16.h>

#define D 64
#define RB 128            // rows per bin (7-bit local row)
#define NB_MAX 1024       // max bins (n_nodes <= 2^17)
#define NBLK 256          // blocks for count/scatter passes (must match!)
#define CAP 5120          // K5 LDS staging capacity (records) = 40 KB

typedef unsigned long long ull;

// ---------------- fallback: round-1 atomic kernel ----------------
__global__ __launch_bounds__(256) void spmm_atomic_kernel(
    const float* __restrict__ x,
    const int*   __restrict__ edge_row,
    const int*   __restrict__ edge_col,
    const float* __restrict__ edge_val,
    float*       __restrict__ out,
    int n_edges)
{
    const int gtid = blockIdx.x * blockDim.x + threadIdx.x;
    const int wave = gtid >> 6;
    const int lane = threadIdx.x & 63;
    if (wave >= n_edges) return;
    const int   r = edge_row[wave];
    const int   c = edge_col[wave];
    const float v = edge_val[wave];
    atomicAdd(&out[(size_t)r * D + lane], v * x[(size_t)c * D + lane]);
}

// ---------------- K1: fused x->fp16 convert + per-block bin counts ----------------
// counts layout TRANSPOSED: counts[bin*NBLK + blk] so K2 is fully coalesced.
// (K1's strided writes land in the L2-resident 800KB counts array — absorbed.)
__global__ __launch_bounds__(256) void count_convert_kernel(
    const float* __restrict__ x, __half2* __restrict__ xh2, int n4,
    const int* __restrict__ rows, int* __restrict__ counts,
    int n_edges, int nb, int chunk)
{
    __shared__ int cnt[NB_MAX];
    const int t = threadIdx.x, blk = blockIdx.x;

    // part A: convert a slice of x to fp16 (independent of part B)
    if (xh2) {
        for (int i = blk * 256 + t; i < n4; i += NBLK * 256) {
            const float4 v = ((const float4*)x)[i];
            xh2[2 * i + 0] = __floats2half2_rn(v.x, v.y);
            xh2[2 * i + 1] = __floats2half2_rn(v.z, v.w);
        }
    }

    // part B: LDS histogram over this block's contiguous edge chunk (int4 loads)
    for (int i = t; i < nb; i += 256) cnt[i] = 0;
    __syncthreads();

    const int e0 = blk * chunk;
    const int e1 = min(e0 + chunk, n_edges);
    for (int i = e0 + t * 4; i < e1; i += 1024) {
        if (i + 4 <= e1) {
            const int4 r4 = *(const int4*)(rows + i);
            atomicAdd(&cnt[r4.x >> 7], 1);
            atomicAdd(&cnt[r4.y >> 7], 1);
            atomicAdd(&cnt[r4.z >> 7], 1);
            atomicAdd(&cnt[r4.w >> 7], 1);
        } else {
            for (int k = i; k < e1; ++k) atomicAdd(&cnt[rows[k] >> 7], 1);
        }
    }
    __syncthreads();
    for (int i = t; i < nb; i += 256) counts[i * NBLK + blk] = cnt[i];
}

// ---------------- K2: per-bin exclusive scan over the NBLK blocks (coalesced) ----
__global__ __launch_bounds__(NBLK) void scan_blocks_kernel(
    int* __restrict__ counts, int* __restrict__ binsum, int nb)
{
    __shared__ int s[NBLK];
    const int b = blockIdx.x, t = threadIdx.x;
    const int mine = counts[b * NBLK + t];      // coalesced
    s[t] = mine;
    for (int off = 1; off < NBLK; off <<= 1) {
        __syncthreads();
        int v = (t >= off) ? s[t - off] : 0;
        __syncthreads();
        s[t] += v;
    }
    counts[b * NBLK + t] = s[t] - mine;         // exclusive within bin, coalesced
    if (t == NBLK - 1) binsum[b] = s[t];
}

// ---------------- K3: exclusive scan over bins -> binbase[nb+1]; zero flags ------
__global__ __launch_bounds__(1024) void scan_bins_kernel(
    const int* __restrict__ binsum, int* __restrict__ binbase,
    int* __restrict__ flags, int nb)
{
    __shared__ int s[1024];
    const int t = threadIdx.x;
    const int mine = (t < nb) ? binsum[t] : 0;
    s[t] = mine;
    for (int off = 1; off < 1024; off <<= 1) {
        __syncthreads();
        int v = (t >= off) ? s[t - off] : 0;
        __syncthreads();
        s[t] += v;
    }
    if (t < nb) { binbase[t] = s[t] - mine; flags[t] = 0; }
    if (t == nb - 1) binbase[nb] = s[t];
}

// ---------------- K4: scatter into PRIVATE per-(block,bin) ranges ----------------
// Same chunking as K1 -> identical edge->block assignment -> counts match.
// rec = [ val:f32 (hi32) | localrow:bits17-23 | col:bits0-16 (lo32) ]
__global__ __launch_bounds__(256) void scatter_kernel(
    const int* __restrict__ rows, const int* __restrict__ cols,
    const float* __restrict__ vals,
    const int* __restrict__ cursorbase, const int* __restrict__ binbase,
    ull* __restrict__ recs, int n_edges, int nb, int chunk)
{
    __shared__ int cur[NB_MAX];
    const int t = threadIdx.x, blk = blockIdx.x;
    for (int i = t; i < nb; i += 256)
        cur[i] = binbase[i] + cursorbase[i * NBLK + blk];   // strided read, L2-hot
    __syncthreads();

    const int e0 = blk * chunk;
    const int e1 = min(e0 + chunk, n_edges);
    for (int i = e0 + t * 4; i < e1; i += 1024) {
        if (i + 4 <= e1) {
            const int4   r4 = *(const int4*)(rows + i);
            const int4   c4 = *(const int4*)(cols + i);
            const float4 v4 = *(const float4*)(vals + i);
            {
                const unsigned lo = ((unsigned)(r4.x & (RB - 1)) << 17) | (unsigned)c4.x;
                const int pos = atomicAdd(&cur[r4.x >> 7], 1);
                recs[pos] = ((ull)__float_as_uint(v4.x) << 32) | (ull)lo;
            }
            {
                const unsigned lo = ((unsigned)(r4.y & (RB - 1)) << 17) | (unsigned)c4.y;
                const int pos = atomicAdd(&cur[r4.y >> 7], 1);
                recs[pos] = ((ull)__float_as_uint(v4.y) << 32) | (ull)lo;
            }
            {
                const unsigned lo = ((unsigned)(r4.z & (RB - 1)) << 17) | (unsigned)c4.z;
                const int pos = atomicAdd(&cur[r4.z >> 7], 1);
                recs[pos] = ((ull)__float_as_uint(v4.z) << 32) | (ull)lo;
            }
            {
                const unsigned lo = ((unsigned)(r4.w & (RB - 1)) << 17) | (unsigned)c4.w;
                const int pos = atomicAdd(&cur[r4.w >> 7], 1);
                recs[pos] = ((ull)__float_as_uint(v4.w) << 32) | (ull)lo;
            }
        } else {
            for (int k = i; k < e1; ++k) {
                const int r = rows[k];
                const unsigned lo = ((unsigned)(r & (RB - 1)) << 17) | (unsigned)cols[k];
                const int pos = atomicAdd(&cur[r >> 7], 1);
                recs[pos] = ((ull)__float_as_uint(vals[k]) << 32) | (ull)lo;
            }
        }
    }
}

// ---------------- K5: in-place per-bin sort to exact row order + row offsets ------
__global__ __launch_bounds__(256) void binsort_kernel(
    ull* __restrict__ recs, const int* __restrict__ binbase,
    int* __restrict__ offsets_row, int* __restrict__ flags,
    int nb, int n_nodes)
{
    __shared__ ull stage[CAP];
    __shared__ int cnt[RB], sc[RB], cur[RB];
    const int b = blockIdx.x, t = threadIdx.x;
    const int s0 = binbase[b], s1 = binbase[b + 1], len = s1 - s0;

    if (len > CAP) { if (t == 0) flags[b] = 1; return; }

    for (int i = t; i < RB; i += 256) cnt[i] = 0;
    __syncthreads();

    for (int i = t; i < len; i += 256) {
        const ull rr = recs[s0 + i];
        stage[i] = rr;
        atomicAdd(&cnt[(int)((rr >> 17) & (RB - 1))], 1);
    }
    __syncthreads();

    if (t < RB) sc[t] = cnt[t];
    for (int off = 1; off < RB; off <<= 1) {
        __syncthreads();
        int v = (t < RB && t >= off) ? sc[t - off] : 0;
        __syncthreads();
        if (t < RB) sc[t] += v;
    }
    __syncthreads();

    if (t < RB) cur[t] = sc[t] - cnt[t];
    if (t <= RB) {
        const int r = b * RB + t;
        if (r <= n_nodes)
            offsets_row[r] = s0 + ((t == RB) ? len : (sc[t] - cnt[t]));
    }
    __syncthreads();

    for (int i = t; i < len; i += 256) {
        const ull rr = stage[i];
        const int p = atomicAdd(&cur[(int)((rr >> 17) & (RB - 1))], 1);
        recs[s0 + p] = rr;
    }
}

// ---------------- K6a: CSR SpMM fp16-x, one wave per row, lane = feature ----------
__global__ __launch_bounds__(256) void spmm_csr_half_kernel(
    const __half* __restrict__ xh,
    const int*   __restrict__ offsets_row,
    const int*   __restrict__ binbase,
    const ull*   __restrict__ recs,
    const int*   __restrict__ flags,
    float*       __restrict__ out,
    int n_nodes)
{
    const int row  = blockIdx.x * 4 + (threadIdx.x >> 6);
    const int lane = threadIdx.x & 63;
    if (row >= n_nodes) return;

    float acc = 0.f;
    const int b = row >> 7;

    if (__builtin_expect(flags[b], 0)) {
        const int s  = binbase[b];
        const int e  = binbase[b + 1];
        const int lr = row & (RB - 1);
        for (int j = s; j < e; ++j) {
            const ull rec = recs[j];
            if ((int)((rec >> 17) & (RB - 1)) == lr) {
                const int   c = (int)((unsigned)rec & 0x1FFFF);
                const float v = __uint_as_float((unsigned)(rec >> 32));
                acc += v * __half2float(xh[(size_t)c * D + lane]);
            }
        }
    } else {
        const int s = offsets_row[row];
        const int e = offsets_row[row + 1];
        int j = s;
        for (; j + 8 <= e; j += 8) {
            float vv[8], xv[8];
            #pragma unroll
            for (int k = 0; k < 8; ++k) {
                const ull rec = recs[j + k];
                vv[k] = __uint_as_float((unsigned)(rec >> 32));
                const int c = (int)((unsigned)rec & 0x1FFFF);
                xv[k] = __half2float(xh[(size_t)c * D + lane]);
            }
            #pragma unroll
            for (int k = 0; k < 8; ++k) acc += vv[k] * xv[k];
        }
        for (; j < e; ++j) {
            const ull rec = recs[j];
            const float v = __uint_as_float((unsigned)(rec >> 32));
            const int   c = (int)((unsigned)rec & 0x1FFFF);
            acc += v * __half2float(xh[(size_t)c * D + lane]);
        }
    }
    out[(size_t)row * D + lane] = acc;
}

// ---------------- K6b: CSR SpMM fp32-x (only if ws can't fit xh) ----------------
__global__ __launch_bounds__(256) void spmm_csr_kernel(
    const float* __restrict__ x,
    const int*   __restrict__ offsets_row,
    const int*   __restrict__ binbase,
    const ull*   __restrict__ recs,
    const int*   __restrict__ flags,
    float*       __restrict__ out,
    int n_nodes)
{
    const int row  = blockIdx.x * 4 + (threadIdx.x >> 6);
    const int lane = threadIdx.x & 63;
    if (row >= n_nodes) return;

    float acc = 0.f;
    const int b = row >> 7;

    if (__builtin_expect(flags[b], 0)) {
        const int s  = binbase[b];
        const int e  = binbase[b + 1];
        const int lr = row & (RB - 1);
        for (int j = s; j < e; ++j) {
            const ull rec = recs[j];
            if ((int)((rec >> 17) & (RB - 1)) == lr) {
                const int   c = (int)((unsigned)rec & 0x1FFFF);
                const float v = __uint_as_float((unsigned)(rec >> 32));
                acc += v * x[(size_t)c * D + lane];
            }
        }
    } else {
        const int s = offsets_row[row];
        const int e = offsets_row[row + 1];
        int j = s;
        for (; j + 8 <= e; j += 8) {
            float vv[8], xv[8];
            #pragma unroll
            for (int k = 0; k < 8; ++k) {
                const ull rec = recs[j + k];
                vv[k] = __uint_as_float((unsigned)(rec >> 32));
                const int c = (int)((unsigned)rec & 0x1FFFF);
                xv[k] = x[(size_t)c * D + lane];
            }
            #pragma unroll
            for (int k = 0; k < 8; ++k) acc += vv[k] * xv[k];
        }
        for (; j < e; ++j) {
            const ull rec = recs[j];
            const float v = __uint_as_float((unsigned)(rec >> 32));
            const int   c = (int)((unsigned)rec & 0x1FFFF);
            acc += v * x[(size_t)c * D + lane];
        }
    }
    out[(size_t)row * D + lane] = acc;
}

static inline size_t align16(size_t v) { return (v + 15) & ~(size_t)15; }

extern "C" void kernel_launch(void* const* d_in, const int* in_sizes, int n_in,
                              void* d_out, int out_size, void* d_ws, size_t ws_size,
                              hipStream_t stream)
{
    // setup_inputs order: t, x, edge_row, edge_col, edge_val
    const float* x        = (const float*)d_in[1];
    const int*   edge_row = (const int*)d_in[2];
    const int*   edge_col = (const int*)d_in[3];
    const float* edge_val = (const float*)d_in[4];
    float*       out      = (float*)d_out;

    const int n_edges = in_sizes[2];
    const int n_nodes = out_size / D;
    const int nb      = (n_nodes + RB - 1) / RB;
    // contiguous per-block edge chunk, multiple of 4 (int4 alignment)
    const int chunk   = (((n_edges + NBLK - 1) / NBLK) + 3) & ~3;

    // workspace carve
    const size_t off_recs    = 0;                                              // n_edges * 8
    const size_t off_counts  = align16(off_recs + (size_t)n_edges * 8);        // nb*NBLK ints
    const size_t off_binsum  = align16(off_counts + (size_t)nb * NBLK * 4);    // nb ints
    const size_t off_binbase = align16(off_binsum + (size_t)nb * 4);           // nb+1 ints
    const size_t off_rowoffs = align16(off_binbase + (size_t)(nb + 1) * 4);    // n_nodes+1 ints
    const size_t off_flags   = align16(off_rowoffs + (size_t)(n_nodes + 1) * 4); // nb ints
    const size_t base_needed = off_flags + (size_t)nb * 4;
    const size_t off_xhalf   = align16(base_needed);                           // n_nodes*D*2 B
    const size_t half_needed = off_xhalf + (size_t)n_nodes * D * 2;
    const bool   use_half    = (ws_size >= half_needed);

    if (ws_size < base_needed || nb > NB_MAX || n_nodes > (1 << 17)) {
        hipMemsetAsync(out, 0, (size_t)out_size * sizeof(float), stream);
        const int n_blocks = (n_edges + 3) / 4;
        spmm_atomic_kernel<<<n_blocks, 256, 0, stream>>>(
            x, edge_row, edge_col, edge_val, out, n_edges);
        return;
    }

    char* ws = (char*)d_ws;
    ull*    recs        = (ull*)(ws + off_recs);
    int*    counts      = (int*)(ws + off_counts);   // [bin][blk]; cursorbase after K2
    int*    binsum      = (int*)(ws + off_binsum);
    int*    binbase     = (int*)(ws + off_binbase);
    int*    offsets_row = (int*)(ws + off_rowoffs);
    int*    flags       = (int*)(ws + off_flags);
    __half* xh          = (__half*)(ws + off_xhalf);

    // K1: fused fp16 convert + per-block bin counts
    const int n4 = (n_nodes * D) / 4;   // D=64 -> divisible by 4
    count_convert_kernel<<<NBLK, 256, 0, stream>>>(
        x, use_half ? (__half2*)xh : (__half2*)nullptr, n4,
        edge_row, counts, n_edges, nb, chunk);
    // K2: per-bin scan over blocks -> private ranges (coalesced)
    scan_blocks_kernel<<<nb, NBLK, 0, stream>>>(counts, binsum, nb);
    // K3: bin bases + flag zeroing
    scan_bins_kernel<<<1, 1024, 0, stream>>>(binsum, binbase, flags, nb);
    // K4: atomic-free scatter into private contiguous ranges (int4 loads)
    scatter_kernel<<<NBLK, 256, 0, stream>>>(edge_row, edge_col, edge_val,
                                             counts, binbase, recs,
                                             n_edges, nb, chunk);
    // K5: per-bin LDS sort to exact row order + row offsets
    binsort_kernel<<<nb, 256, 0, stream>>>(recs, binbase, offsets_row, flags,
                                           nb, n_nodes);
    // K6: CSR SpMM, one wave per row
    if (use_half)
        spmm_csr_half_kernel<<<(n_nodes + 3) / 4, 256, 0, stream>>>(
            xh, offsets_row, binbase, recs, flags, out, n_nodes);
    else
        spmm_csr_kernel<<<(n_nodes + 3) / 4, 256, 0, stream>>>(
            x, offsets_row, binbase, recs, flags, out, n_nodes);
}

// Round 11
// 277.917 us; speedup vs baseline: 1.1745x; 1.1046x over previous
//
#include <hip/hip_runtime.h>
#include <hip/hip_bf16.h>
#include <hip/hip_fp16.h>

#define D 64
#define RB 128            // rows per bin (7-bit local row)
#define NB_MAX 1024       // max bins (n_nodes <= 2^17)
#define NBLK1 512         // P1 blocks (2/CU, 8 waves/CU)
#define P1CAP 6272        // P1 LDS stage capacity (recs) = 50,176 B
#define CAP 5120          // P4 LDS stage capacity (recs) = 40 KB

typedef unsigned long long ull;
typedef unsigned short u16;

// rec = [ val:f32 (hi32) | localrow:bits17-23 | col:bits0-16 ]
__device__ __forceinline__ ull pack_rec(float v, int r, int c) {
    return ((ull)__float_as_uint(v) << 32) |
           (ull)(((unsigned)(r & (RB - 1)) << 17) | (unsigned)c);
}

// ---------------- fallback: round-1 atomic kernel ----------------
__global__ __launch_bounds__(256) void spmm_atomic_kernel(
    const float* __restrict__ x,
    const int*   __restrict__ edge_row,
    const int*   __restrict__ edge_col,
    const float* __restrict__ edge_val,
    float*       __restrict__ out,
    int n_edges)
{
    const int gtid = blockIdx.x * blockDim.x + threadIdx.x;
    const int wave = gtid >> 6;
    const int lane = threadIdx.x & 63;
    if (wave >= n_edges) return;
    const int   r = edge_row[wave];
    const int   c = edge_col[wave];
    const float v = edge_val[wave];
    atomicAdd(&out[(size_t)r * D + lane], v * x[(size_t)c * D + lane]);
}

// ---------------- P1: per-block LDS counting sort + identity-coalesced writeout ----
// Each block owns a contiguous edge chunk; sorts it by bin in LDS; writes
// staged[blk*chunk + i] fully coalesced. No global atomics, no cursor coupling.
__global__ __launch_bounds__(256) void p1_localsort_kernel(
    const int* __restrict__ rows, const int* __restrict__ cols,
    const float* __restrict__ vals,
    ull* __restrict__ staged, u16* __restrict__ counts, u16* __restrict__ startpos,
    int n_edges, int nb, int chunk)
{
    __shared__ ull stage[P1CAP];
    __shared__ int cnt[NB_MAX];
    __shared__ int s[256];
    const int t = threadIdx.x, blk = blockIdx.x;
    const int e0 = blk * chunk;
    const int e1 = min(e0 + chunk, n_edges);
    const int len = e1 - e0;

    for (int i = t; i < nb; i += 256) cnt[i] = 0;
    __syncthreads();

    // pass 1: histogram rows (int4)
    for (int i = e0 + t * 4; i < e1; i += 1024) {
        if (i + 4 <= e1) {
            const int4 r4 = *(const int4*)(rows + i);
            atomicAdd(&cnt[r4.x >> 7], 1);
            atomicAdd(&cnt[r4.y >> 7], 1);
            atomicAdd(&cnt[r4.z >> 7], 1);
            atomicAdd(&cnt[r4.w >> 7], 1);
        } else {
            for (int k = i; k < e1; ++k) atomicAdd(&cnt[rows[k] >> 7], 1);
        }
    }
    __syncthreads();

    // write counts (coalesced) + in-place exclusive scan of cnt
    int v[4], pre[4], sum = 0;
    const int base = t * 4;
    #pragma unroll
    for (int k = 0; k < 4; ++k) {
        const int idx = base + k;
        const int c = (idx < nb) ? cnt[idx] : 0;
        if (idx < nb) counts[(size_t)blk * nb + idx] = (u16)c;
        pre[k] = sum; sum += c; v[k] = c;
    }
    s[t] = sum;
    for (int off = 1; off < 256; off <<= 1) {
        __syncthreads();
        const int w = (t >= off) ? s[t - off] : 0;
        __syncthreads();
        s[t] += w;
    }
    const int texcl = s[t] - sum;
    __syncthreads();
    #pragma unroll
    for (int k = 0; k < 4; ++k) {
        const int idx = base + k;
        if (idx < nb) {
            const int e = texcl + pre[k];
            cnt[idx] = e;                                   // becomes cursor
            startpos[(size_t)blk * nb + idx] = (u16)e;
        }
    }
    __syncthreads();

    // pass 2: scatter into LDS stage
    for (int i = e0 + t * 4; i < e1; i += 1024) {
        if (i + 4 <= e1) {
            const int4   r4 = *(const int4*)(rows + i);
            const int4   c4 = *(const int4*)(cols + i);
            const float4 v4 = *(const float4*)(vals + i);
            int p;
            p = atomicAdd(&cnt[r4.x >> 7], 1); stage[p] = pack_rec(v4.x, r4.x, c4.x);
            p = atomicAdd(&cnt[r4.y >> 7], 1); stage[p] = pack_rec(v4.y, r4.y, c4.y);
            p = atomicAdd(&cnt[r4.z >> 7], 1); stage[p] = pack_rec(v4.z, r4.z, c4.z);
            p = atomicAdd(&cnt[r4.w >> 7], 1); stage[p] = pack_rec(v4.w, r4.w, c4.w);
        } else {
            for (int k = i; k < e1; ++k) {
                const int p = atomicAdd(&cnt[rows[k] >> 7], 1);
                stage[p] = pack_rec(vals[k], rows[k], cols[k]);
            }
        }
    }
    __syncthreads();

    // identity-coalesced writeout
    for (int i = t; i < len; i += 256)
        staged[(size_t)blk * chunk + i] = stage[i];
}

// ---------------- P2: binsum[b] = sum over blocks of counts[blk][b] ----------------
__global__ __launch_bounds__(256) void p2_binsum_kernel(
    const u16* __restrict__ counts, int* __restrict__ binsum, int nb)
{
    __shared__ int s[256];
    const int b = blockIdx.x, t = threadIdx.x;
    int acc = (int)counts[(size_t)t * nb + b] + (int)counts[(size_t)(t + 256) * nb + b];
    s[t] = acc;
    __syncthreads();
    for (int off = 128; off > 0; off >>= 1) {
        if (t < off) s[t] += s[t + off];
        __syncthreads();
    }
    if (t == 0) binsum[b] = s[0];
}

// ---------------- P3: exclusive scan over bins -> binbase[nb+1]; zero flags --------
__global__ __launch_bounds__(1024) void p3_scanbins_kernel(
    const int* __restrict__ binsum, int* __restrict__ binbase,
    int* __restrict__ flags, int nb)
{
    __shared__ int s[1024];
    const int t = threadIdx.x;
    const int mine = (t < nb) ? binsum[t] : 0;
    s[t] = mine;
    for (int off = 1; off < 1024; off <<= 1) {
        __syncthreads();
        const int v = (t >= off) ? s[t - off] : 0;
        __syncthreads();
        s[t] += v;
    }
    if (t < nb) { binbase[t] = s[t] - mine; flags[t] = 0; }
    if (t == nb - 1) binbase[nb] = s[t];
}

// ---------------- P4: per-bin gather + LDS key-sort (localrow | colslice) ----------
__global__ __launch_bounds__(256) void p4_binsort_kernel(
    const ull* __restrict__ staged, const u16* __restrict__ counts,
    const u16* __restrict__ startpos, const int* __restrict__ binbase,
    ull* __restrict__ recs, int* __restrict__ offsets_row, int* __restrict__ flags,
    int nb, int n_nodes, int chunk)
{
    __shared__ ull stage[CAP];
    __shared__ int doff[NBLK1 + 1];
    __shared__ int srcs[NBLK1];
    __shared__ int cnt[1024];
    __shared__ int s[256];
    const int b = blockIdx.x, t = threadIdx.x;
    const int s0 = binbase[b];

    // load run lengths + starts; exclusive scan over 512 runs (2 per thread)
    const int la = (int)counts[(size_t)(2 * t) * nb + b];
    const int lb = (int)counts[(size_t)(2 * t + 1) * nb + b];
    srcs[2 * t]     = (int)startpos[(size_t)(2 * t) * nb + b];
    srcs[2 * t + 1] = (int)startpos[(size_t)(2 * t + 1) * nb + b];
    const int mysum = la + lb;
    s[t] = mysum;
    for (int off = 1; off < 256; off <<= 1) {
        __syncthreads();
        const int w = (t >= off) ? s[t - off] : 0;
        __syncthreads();
        s[t] += w;
    }
    const int excl = s[t] - mysum;
    doff[2 * t] = excl;
    doff[2 * t + 1] = excl + la;
    if (t == 255) doff[NBLK1] = s[255];
    __syncthreads();
    const int len = doff[NBLK1];

    if (len > CAP) {
        // overflow: bin-grouped raw copy (K6 filter path)
        if (t == 0) flags[b] = 1;
        for (int i = t; i < len; i += 256) {
            int lo = 0, hi = NBLK1 - 1;
            while (lo < hi) {
                const int mid = (lo + hi + 1) >> 1;
                if (doff[mid] <= i) lo = mid; else hi = mid - 1;
            }
            recs[s0 + i] = staged[(size_t)lo * chunk + srcs[lo] + (i - doff[lo])];
        }
        // boundary offset for previous bin's last row
        if (t == 0 && b * RB <= n_nodes) offsets_row[b * RB] = s0;
        return;
    }

    for (int i = t; i < 1024; i += 256) cnt[i] = 0;
    __syncthreads();

    // gather runs into LDS (coalesced 64B bursts within runs) + key histogram
    for (int i = t; i < len; i += 256) {
        int lo = 0, hi = NBLK1 - 1;
        while (lo < hi) {
            const int mid = (lo + hi + 1) >> 1;
            if (doff[mid] <= i) lo = mid; else hi = mid - 1;
        }
        const ull rr = staged[(size_t)lo * chunk + srcs[lo] + (i - doff[lo])];
        stage[i] = rr;
        const int key = ((int)((rr >> 17) & (RB - 1)) << 3) |
                        (int)(((unsigned)rr & 0x1FFFF) >> 14);
        atomicAdd(&cnt[key], 1);
    }
    __syncthreads();

    // exclusive scan of 1024 keys (4 per thread) -> cnt becomes cursor
    int v[4], pre[4], sum = 0;
    const int base = t * 4;
    #pragma unroll
    for (int k = 0; k < 4; ++k) { v[k] = cnt[base + k]; pre[k] = sum; sum += v[k]; }
    s[t] = sum;
    for (int off = 1; off < 256; off <<= 1) {
        __syncthreads();
        const int w = (t >= off) ? s[t - off] : 0;
        __syncthreads();
        s[t] += w;
    }
    const int texcl = s[t] - sum;
    __syncthreads();
    #pragma unroll
    for (int k = 0; k < 4; ++k) cnt[base + k] = texcl + pre[k];
    __syncthreads();

    // emit row offsets (row lr starts at key lr*8); boundary entry at t==RB
    if (t <= RB) {
        const int r = b * RB + t;
        if (r <= n_nodes)
            offsets_row[r] = s0 + ((t == RB) ? len : cnt[t << 3]);
    }
    __syncthreads();

    // permute to final (localrow, colslice) order; writes stay in this bin's segment
    for (int i = t; i < len; i += 256) {
        const ull rr = stage[i];
        const int key = ((int)((rr >> 17) & (RB - 1)) << 3) |
                        (int)(((unsigned)rr & 0x1FFFF) >> 14);
        const int p = atomicAdd(&cnt[key], 1);
        recs[s0 + p] = rr;
    }
}

// ---------------- P0: x -> fp16 (runs after P4; xh reuses the staged region) -------
__global__ void tohalf_kernel(const float* __restrict__ x,
                              __half2* __restrict__ xh2, int n4)
{
    for (int i = blockIdx.x * blockDim.x + threadIdx.x; i < n4;
         i += gridDim.x * blockDim.x) {
        const float4 v = ((const float4*)x)[i];
        xh2[2 * i + 0] = __floats2half2_rn(v.x, v.y);
        xh2[2 * i + 1] = __floats2half2_rn(v.z, v.w);
    }
}

// ---------------- K6: CSR SpMM fp16-x, one wave per row, lane = feature ------------
__global__ __launch_bounds__(256) void spmm_csr_half_kernel(
    const __half* __restrict__ xh,
    const int*   __restrict__ offsets_row,
    const int*   __restrict__ binbase,
    const ull*   __restrict__ recs,
    const int*   __restrict__ flags,
    float*       __restrict__ out,
    int n_nodes)
{
    const int row  = blockIdx.x * 4 + (threadIdx.x >> 6);
    const int lane = threadIdx.x & 63;
    if (row >= n_nodes) return;

    float acc = 0.f;
    const int b = row >> 7;

    if (__builtin_expect(flags[b], 0)) {
        const int s  = binbase[b];
        const int e  = binbase[b + 1];
        const int lr = row & (RB - 1);
        for (int j = s; j < e; ++j) {
            const ull rec = recs[j];
            if ((int)((rec >> 17) & (RB - 1)) == lr) {
                const int   c = (int)((unsigned)rec & 0x1FFFF);
                const float v = __uint_as_float((unsigned)(rec >> 32));
                acc += v * __half2float(xh[(size_t)c * D + lane]);
            }
        }
    } else {
        const int s = offsets_row[row];
        const int e = offsets_row[row + 1];
        int j = s;
        for (; j + 8 <= e; j += 8) {
            float vv[8], xv[8];
            #pragma unroll
            for (int k = 0; k < 8; ++k) {
                const ull rec = recs[j + k];
                vv[k] = __uint_as_float((unsigned)(rec >> 32));
                const int c = (int)((unsigned)rec & 0x1FFFF);
                xv[k] = __half2float(xh[(size_t)c * D + lane]);
            }
            #pragma unroll
            for (int k = 0; k < 8; ++k) acc += vv[k] * xv[k];
        }
        for (; j < e; ++j) {
            const ull rec = recs[j];
            const float v = __uint_as_float((unsigned)(rec >> 32));
            const int   c = (int)((unsigned)rec & 0x1FFFF);
            acc += v * __half2float(xh[(size_t)c * D + lane]);
        }
    }
    out[(size_t)row * D + lane] = acc;
}

static inline size_t align16(size_t v) { return (v + 15) & ~(size_t)15; }

extern "C" void kernel_launch(void* const* d_in, const int* in_sizes, int n_in,
                              void* d_out, int out_size, void* d_ws, size_t ws_size,
                              hipStream_t stream)
{
    // setup_inputs order: t, x, edge_row, edge_col, edge_val
    const float* x        = (const float*)d_in[1];
    const int*   edge_row = (const int*)d_in[2];
    const int*   edge_col = (const int*)d_in[3];
    const float* edge_val = (const float*)d_in[4];
    float*       out      = (float*)d_out;

    const int n_edges = in_sizes[2];
    const int n_nodes = out_size / D;
    const int nb      = (n_nodes + RB - 1) / RB;
    const int chunk   = (((n_edges + NBLK1 - 1) / NBLK1) + 3) & ~3;  // x4 for int4

    // workspace carve
    const size_t off_recs    = 0;                                               // n_edges*8
    const size_t off_staged  = align16(off_recs + (size_t)n_edges * 8);         // NBLK1*chunk*8 (xh reuse)
    const size_t off_counts  = align16(off_staged + (size_t)NBLK1 * chunk * 8); // NBLK1*nb u16
    const size_t off_start   = align16(off_counts + (size_t)NBLK1 * nb * 2);    // NBLK1*nb u16
    const size_t off_binsum  = align16(off_start + (size_t)NBLK1 * nb * 2);     // nb ints
    const size_t off_binbase = align16(off_binsum + (size_t)nb * 4);            // nb+1 ints
    const size_t off_rowoffs = align16(off_binbase + (size_t)(nb + 1) * 4);     // n_nodes+1 ints
    const size_t off_flags   = align16(off_rowoffs + (size_t)(n_nodes + 1) * 4);// nb ints
    const size_t ws_needed   = off_flags + (size_t)nb * 4;
    const size_t xh_bytes    = (size_t)n_nodes * D * 2;   // must fit in staged region

    if (ws_size < ws_needed || nb > NB_MAX || n_nodes > (1 << 17) ||
        chunk > P1CAP || xh_bytes > (size_t)NBLK1 * chunk * 8) {
        hipMemsetAsync(out, 0, (size_t)out_size * sizeof(float), stream);
        const int n_blocks = (n_edges + 3) / 4;
        spmm_atomic_kernel<<<n_blocks, 256, 0, stream>>>(
            x, edge_row, edge_col, edge_val, out, n_edges);
        return;
    }

    char* ws = (char*)d_ws;
    ull*    recs        = (ull*)(ws + off_recs);
    ull*    staged      = (ull*)(ws + off_staged);
    u16*    counts      = (u16*)(ws + off_counts);
    u16*    startpos    = (u16*)(ws + off_start);
    int*    binsum      = (int*)(ws + off_binsum);
    int*    binbase     = (int*)(ws + off_binbase);
    int*    offsets_row = (int*)(ws + off_rowoffs);
    int*    flags       = (int*)(ws + off_flags);
    __half* xh          = (__half*)(ws + off_staged);   // reuses staged AFTER P4

    // P1: per-block LDS counting sort -> staged (all record writes coalesced)
    p1_localsort_kernel<<<NBLK1, 256, 0, stream>>>(
        edge_row, edge_col, edge_val, staged, counts, startpos,
        n_edges, nb, chunk);
    // P2: per-bin totals
    p2_binsum_kernel<<<nb, 256, 0, stream>>>(counts, binsum, nb);
    // P3: bin bases + flag zeroing
    p3_scanbins_kernel<<<1, 1024, 0, stream>>>(binsum, binbase, flags, nb);
    // P4: gather runs + sort by (localrow | colslice) -> final recs + row offsets
    p4_binsort_kernel<<<nb, 256, 0, stream>>>(
        staged, counts, startpos, binbase, recs, offsets_row, flags,
        nb, n_nodes, chunk);
    // P0: x -> fp16 into the (now free) staged region
    const int n4 = (n_nodes * D) / 4;
    tohalf_kernel<<<2048, 256, 0, stream>>>(x, (__half2*)xh, n4);
    // K6: CSR SpMM, one wave per row
    spmm_csr_half_kernel<<<(n_nodes + 3) / 4, 256, 0, stream>>>(
        xh, offsets_row, binbase, recs, flags, out, n_nodes);
}

// Round 12
// 276.701 us; speedup vs baseline: 1.1797x; 1.0044x over previous
//
#include <hip/hip_runtime.h>
#include <hip/hip_bf16.h>
#include <hip/hip_fp16.h>

#define D 64
#define RB 128            // rows per bin (7-bit local row)
#define NB_MAX 1024       // max bins (n_nodes <= 2^17)
#define NBLK1 512         // P1 blocks (2/CU, 8 waves/CU)
#define P1CAP 6272        // P1 LDS stage capacity (recs) = 50,176 B
#define CAP 5120          // P4 LDS stage capacity (recs) = 40 KB

typedef unsigned long long ull;
typedef unsigned short u16;

// rec = [ val:f32 (hi32) | localrow:bits17-23 | col:bits0-16 ]
__device__ __forceinline__ ull pack_rec(float v, int r, int c) {
    return ((ull)__float_as_uint(v) << 32) |
           (ull)(((unsigned)(r & (RB - 1)) << 17) | (unsigned)c);
}

// ---------------- fallback: round-1 atomic kernel ----------------
__global__ __launch_bounds__(256) void spmm_atomic_kernel(
    const float* __restrict__ x,
    const int*   __restrict__ edge_row,
    const int*   __restrict__ edge_col,
    const float* __restrict__ edge_val,
    float*       __restrict__ out,
    int n_edges)
{
    const int gtid = blockIdx.x * blockDim.x + threadIdx.x;
    const int wave = gtid >> 6;
    const int lane = threadIdx.x & 63;
    if (wave >= n_edges) return;
    const int   r = edge_row[wave];
    const int   c = edge_col[wave];
    const float v = edge_val[wave];
    atomicAdd(&out[(size_t)r * D + lane], v * x[(size_t)c * D + lane]);
}

// ---------------- P1: per-block LDS counting sort + identity-coalesced writeout ----
// counts/startpos layout: [bin][blk] (transposed) -> P2/P4 reads coalesced;
// P1's strided u16 writes hit a 100KB L2-resident array (absorbed).
__global__ __launch_bounds__(256) void p1_localsort_kernel(
    const int* __restrict__ rows, const int* __restrict__ cols,
    const float* __restrict__ vals,
    ull* __restrict__ staged, u16* __restrict__ counts, u16* __restrict__ startpos,
    int n_edges, int nb, int chunk)
{
    __shared__ ull stage[P1CAP];
    __shared__ int cnt[NB_MAX];
    __shared__ int s[256];
    const int t = threadIdx.x, blk = blockIdx.x;
    const int e0 = blk * chunk;
    const int e1 = min(e0 + chunk, n_edges);
    const int len = e1 - e0;

    for (int i = t; i < nb; i += 256) cnt[i] = 0;
    __syncthreads();

    // pass 1: histogram rows (int4)
    for (int i = e0 + t * 4; i < e1; i += 1024) {
        if (i + 4 <= e1) {
            const int4 r4 = *(const int4*)(rows + i);
            atomicAdd(&cnt[r4.x >> 7], 1);
            atomicAdd(&cnt[r4.y >> 7], 1);
            atomicAdd(&cnt[r4.z >> 7], 1);
            atomicAdd(&cnt[r4.w >> 7], 1);
        } else {
            for (int k = i; k < e1; ++k) atomicAdd(&cnt[rows[k] >> 7], 1);
        }
    }
    __syncthreads();

    // write counts + in-place exclusive scan of cnt
    int pre[4], sum = 0;
    const int base = t * 4;
    #pragma unroll
    for (int k = 0; k < 4; ++k) {
        const int idx = base + k;
        const int c = (idx < nb) ? cnt[idx] : 0;
        if (idx < nb) counts[(size_t)idx * NBLK1 + blk] = (u16)c;
        pre[k] = sum; sum += c;
    }
    s[t] = sum;
    for (int off = 1; off < 256; off <<= 1) {
        __syncthreads();
        const int w = (t >= off) ? s[t - off] : 0;
        __syncthreads();
        s[t] += w;
    }
    const int texcl = s[t] - sum;
    __syncthreads();
    #pragma unroll
    for (int k = 0; k < 4; ++k) {
        const int idx = base + k;
        if (idx < nb) {
            const int e = texcl + pre[k];
            cnt[idx] = e;                                   // becomes cursor
            startpos[(size_t)idx * NBLK1 + blk] = (u16)e;
        }
    }
    __syncthreads();

    // pass 2: scatter into LDS stage
    for (int i = e0 + t * 4; i < e1; i += 1024) {
        if (i + 4 <= e1) {
            const int4   r4 = *(const int4*)(rows + i);
            const int4   c4 = *(const int4*)(cols + i);
            const float4 v4 = *(const float4*)(vals + i);
            int p;
            p = atomicAdd(&cnt[r4.x >> 7], 1); stage[p] = pack_rec(v4.x, r4.x, c4.x);
            p = atomicAdd(&cnt[r4.y >> 7], 1); stage[p] = pack_rec(v4.y, r4.y, c4.y);
            p = atomicAdd(&cnt[r4.z >> 7], 1); stage[p] = pack_rec(v4.z, r4.z, c4.z);
            p = atomicAdd(&cnt[r4.w >> 7], 1); stage[p] = pack_rec(v4.w, r4.w, c4.w);
        } else {
            for (int k = i; k < e1; ++k) {
                const int p = atomicAdd(&cnt[rows[k] >> 7], 1);
                stage[p] = pack_rec(vals[k], rows[k], cols[k]);
            }
        }
    }
    __syncthreads();

    // identity-coalesced writeout
    for (int i = t; i < len; i += 256)
        staged[(size_t)blk * chunk + i] = stage[i];
}

// ---------------- P2: binsum[b] = sum over blocks of counts[b][blk] (coalesced) ----
__global__ __launch_bounds__(256) void p2_binsum_kernel(
    const u16* __restrict__ counts, int* __restrict__ binsum, int nb)
{
    __shared__ int s[256];
    const int b = blockIdx.x, t = threadIdx.x;
    const int acc = (int)counts[(size_t)b * NBLK1 + t] +
                    (int)counts[(size_t)b * NBLK1 + t + 256];
    s[t] = acc;
    __syncthreads();
    for (int off = 128; off > 0; off >>= 1) {
        if (t < off) s[t] += s[t + off];
        __syncthreads();
    }
    if (t == 0) binsum[b] = s[0];
}

// ---------------- P3: exclusive scan over bins -> binbase[nb+1]; zero flags --------
__global__ __launch_bounds__(1024) void p3_scanbins_kernel(
    const int* __restrict__ binsum, int* __restrict__ binbase,
    int* __restrict__ flags, int nb)
{
    __shared__ int s[1024];
    const int t = threadIdx.x;
    const int mine = (t < nb) ? binsum[t] : 0;
    s[t] = mine;
    for (int off = 1; off < 1024; off <<= 1) {
        __syncthreads();
        const int v = (t >= off) ? s[t - off] : 0;
        __syncthreads();
        s[t] += v;
    }
    if (t < nb) { binbase[t] = s[t] - mine; flags[t] = 0; }
    if (t == nb - 1) binbase[nb] = s[t];
}

// ---------------- P4: per-bin gather + LDS key-sort (localrow | colslice) ----------
__global__ __launch_bounds__(256) void p4_binsort_kernel(
    const ull* __restrict__ staged, const u16* __restrict__ counts,
    const u16* __restrict__ startpos, const int* __restrict__ binbase,
    ull* __restrict__ recs, int* __restrict__ offsets_row, int* __restrict__ flags,
    int nb, int n_nodes, int chunk)
{
    __shared__ ull stage[CAP];
    __shared__ int doff[NBLK1 + 1];
    __shared__ int srcs[NBLK1];
    __shared__ int cnt[1024];
    __shared__ int s[256];
    const int b = blockIdx.x, t = threadIdx.x;
    const int s0 = binbase[b];

    // load run lengths + starts (coalesced); exclusive scan over 512 runs
    const int la = (int)counts[(size_t)b * NBLK1 + 2 * t];
    const int lb = (int)counts[(size_t)b * NBLK1 + 2 * t + 1];
    srcs[2 * t]     = (int)startpos[(size_t)b * NBLK1 + 2 * t];
    srcs[2 * t + 1] = (int)startpos[(size_t)b * NBLK1 + 2 * t + 1];
    const int mysum = la + lb;
    s[t] = mysum;
    for (int off = 1; off < 256; off <<= 1) {
        __syncthreads();
        const int w = (t >= off) ? s[t - off] : 0;
        __syncthreads();
        s[t] += w;
    }
    const int excl = s[t] - mysum;
    doff[2 * t] = excl;
    doff[2 * t + 1] = excl + la;
    if (t == 255) doff[NBLK1] = s[255];
    __syncthreads();
    const int len = doff[NBLK1];

    if (len > CAP) {
        // overflow: bin-grouped raw copy (K6 filter path)
        if (t == 0) flags[b] = 1;
        for (int i = t; i < len; i += 256) {
            int lo = 0, hi = NBLK1 - 1;
            while (lo < hi) {
                const int mid = (lo + hi + 1) >> 1;
                if (doff[mid] <= i) lo = mid; else hi = mid - 1;
            }
            recs[s0 + i] = staged[(size_t)lo * chunk + srcs[lo] + (i - doff[lo])];
        }
        if (t == 0 && b * RB <= n_nodes) offsets_row[b * RB] = s0;
        return;
    }

    for (int i = t; i < 1024; i += 256) cnt[i] = 0;
    __syncthreads();

    // gather runs into LDS + key histogram
    for (int i = t; i < len; i += 256) {
        int lo = 0, hi = NBLK1 - 1;
        while (lo < hi) {
            const int mid = (lo + hi + 1) >> 1;
            if (doff[mid] <= i) lo = mid; else hi = mid - 1;
        }
        const ull rr = staged[(size_t)lo * chunk + srcs[lo] + (i - doff[lo])];
        stage[i] = rr;
        const int key = ((int)((rr >> 17) & (RB - 1)) << 3) |
                        (int)(((unsigned)rr & 0x1FFFF) >> 14);
        atomicAdd(&cnt[key], 1);
    }
    __syncthreads();

    // exclusive scan of 1024 keys (4 per thread) -> cnt becomes cursor
    int v[4], pre[4], sum = 0;
    const int base = t * 4;
    #pragma unroll
    for (int k = 0; k < 4; ++k) { v[k] = cnt[base + k]; pre[k] = sum; sum += v[k]; }
    s[t] = sum;
    for (int off = 1; off < 256; off <<= 1) {
        __syncthreads();
        const int w = (t >= off) ? s[t - off] : 0;
        __syncthreads();
        s[t] += w;
    }
    const int texcl = s[t] - sum;
    __syncthreads();
    #pragma unroll
    for (int k = 0; k < 4; ++k) cnt[base + k] = texcl + pre[k];
    __syncthreads();

    // emit row offsets (row lr starts at key lr*8)
    if (t <= RB) {
        const int r = b * RB + t;
        if (r <= n_nodes)
            offsets_row[r] = s0 + ((t == RB) ? len : cnt[t << 3]);
    }
    __syncthreads();

    // permute to final (localrow, colslice) order
    for (int i = t; i < len; i += 256) {
        const ull rr = stage[i];
        const int key = ((int)((rr >> 17) & (RB - 1)) << 3) |
                        (int)(((unsigned)rr & 0x1FFFF) >> 14);
        const int p = atomicAdd(&cnt[key], 1);
        recs[s0 + p] = rr;
    }
}

// ---------------- P0: x -> fp16 (xh reuses the staged region after P4) -------------
__global__ void tohalf_kernel(const float* __restrict__ x,
                              __half2* __restrict__ xh2, int n4)
{
    for (int i = blockIdx.x * blockDim.x + threadIdx.x; i < n4;
         i += gridDim.x * blockDim.x) {
        const float4 v = ((const float4*)x)[i];
        xh2[2 * i + 0] = __floats2half2_rn(v.x, v.y);
        xh2[2 * i + 1] = __floats2half2_rn(v.z, v.w);
    }
}

// ---------------- K6: CSR SpMM fp16-x, wave/row, FORCED ILP-8 gather pipeline ------
// Round-11 evidence: compiler serialized the batch (VGPR=20 -> ILP~1, 19cyc/line
// latency wall). Split issue/consume + sched_barrier(0) keeps 8 gathers in flight.
__global__ __launch_bounds__(256, 8) void spmm_csr_half_kernel(
    const __half* __restrict__ xh,
    const int*   __restrict__ offsets_row,
    const int*   __restrict__ binbase,
    const ull*   __restrict__ recs,
    const int*   __restrict__ flags,
    float*       __restrict__ out,
    int n_nodes)
{
    const int row  = blockIdx.x * 4 + (threadIdx.x >> 6);
    const int lane = threadIdx.x & 63;
    if (row >= n_nodes) return;

    float acc = 0.f;
    const int b = row >> 7;

    if (__builtin_expect(flags[b], 0)) {
        const int s  = binbase[b];
        const int e  = binbase[b + 1];
        const int lr = row & (RB - 1);
        for (int j = s; j < e; ++j) {
            const ull rec = recs[j];
            if ((int)((rec >> 17) & (RB - 1)) == lr) {
                const int   c = (int)((unsigned)rec & 0x1FFFF);
                const float v = __uint_as_float((unsigned)(rec >> 32));
                acc += v * __half2float(xh[(size_t)c * D + lane]);
            }
        }
    } else {
        const int s = offsets_row[row];
        const int e = offsets_row[row + 1];
        int j = s;
        for (; j + 8 <= e; j += 8) {
            float vv[8];
            int   aa[8];
            #pragma unroll
            for (int k = 0; k < 8; ++k) {
                const ull rec = recs[j + k];
                vv[k] = __uint_as_float((unsigned)(rec >> 32));
                aa[k] = (int)((unsigned)rec & 0x1FFFF) * D + lane;
            }
            __half hv[8];
            #pragma unroll
            for (int k = 0; k < 8; ++k)
                hv[k] = xh[aa[k]];                 // 8 gathers ISSUED here
            __builtin_amdgcn_sched_barrier(0);     // ...and kept in flight
            #pragma unroll
            for (int k = 0; k < 8; ++k)
                acc += vv[k] * __half2float(hv[k]);
        }
        for (; j < e; ++j) {
            const ull rec = recs[j];
            const float v = __uint_as_float((unsigned)(rec >> 32));
            const int   c = (int)((unsigned)rec & 0x1FFFF);
            acc += v * __half2float(xh[(size_t)c * D + lane]);
        }
    }
    out[(size_t)row * D + lane] = acc;
}

static inline size_t align16(size_t v) { return (v + 15) & ~(size_t)15; }

extern "C" void kernel_launch(void* const* d_in, const int* in_sizes, int n_in,
                              void* d_out, int out_size, void* d_ws, size_t ws_size,
                              hipStream_t stream)
{
    // setup_inputs order: t, x, edge_row, edge_col, edge_val
    const float* x        = (const float*)d_in[1];
    const int*   edge_row = (const int*)d_in[2];
    const int*   edge_col = (const int*)d_in[3];
    const float* edge_val = (const float*)d_in[4];
    float*       out      = (float*)d_out;

    const int n_edges = in_sizes[2];
    const int n_nodes = out_size / D;
    const int nb      = (n_nodes + RB - 1) / RB;
    const int chunk   = (((n_edges + NBLK1 - 1) / NBLK1) + 3) & ~3;  // x4 for int4

    // workspace carve
    const size_t off_recs    = 0;                                               // n_edges*8
    const size_t off_staged  = align16(off_recs + (size_t)n_edges * 8);         // NBLK1*chunk*8 (xh reuse)
    const size_t off_counts  = align16(off_staged + (size_t)NBLK1 * chunk * 8); // nb*NBLK1 u16
    const size_t off_start   = align16(off_counts + (size_t)nb * NBLK1 * 2);    // nb*NBLK1 u16
    const size_t off_binsum  = align16(off_start + (size_t)nb * NBLK1 * 2);     // nb ints
    const size_t off_binbase = align16(off_binsum + (size_t)nb * 4);            // nb+1 ints
    const size_t off_rowoffs = align16(off_binbase + (size_t)(nb + 1) * 4);     // n_nodes+1 ints
    const size_t off_flags   = align16(off_rowoffs + (size_t)(n_nodes + 1) * 4);// nb ints
    const size_t ws_needed   = off_flags + (size_t)nb * 4;
    const size_t xh_bytes    = (size_t)n_nodes * D * 2;   // must fit in staged region

    if (ws_size < ws_needed || nb > NB_MAX || n_nodes > (1 << 17) ||
        chunk > P1CAP || xh_bytes > (size_t)NBLK1 * chunk * 8) {
        hipMemsetAsync(out, 0, (size_t)out_size * sizeof(float), stream);
        const int n_blocks = (n_edges + 3) / 4;
        spmm_atomic_kernel<<<n_blocks, 256, 0, stream>>>(
            x, edge_row, edge_col, edge_val, out, n_edges);
        return;
    }

    char* ws = (char*)d_ws;
    ull*    recs        = (ull*)(ws + off_recs);
    ull*    staged      = (ull*)(ws + off_staged);
    u16*    counts      = (u16*)(ws + off_counts);
    u16*    startpos    = (u16*)(ws + off_start);
    int*    binsum      = (int*)(ws + off_binsum);
    int*    binbase     = (int*)(ws + off_binbase);
    int*    offsets_row = (int*)(ws + off_rowoffs);
    int*    flags       = (int*)(ws + off_flags);
    __half* xh          = (__half*)(ws + off_staged);   // reuses staged AFTER P4

    // P1: per-block LDS counting sort -> staged (all record writes coalesced)
    p1_localsort_kernel<<<NBLK1, 256, 0, stream>>>(
        edge_row, edge_col, edge_val, staged, counts, startpos,
        n_edges, nb, chunk);
    // P2: per-bin totals
    p2_binsum_kernel<<<nb, 256, 0, stream>>>(counts, binsum, nb);
    // P3: bin bases + flag zeroing
    p3_scanbins_kernel<<<1, 1024, 0, stream>>>(binsum, binbase, flags, nb);
    // P4: gather runs + sort by (localrow | colslice) -> final recs + row offsets
    p4_binsort_kernel<<<nb, 256, 0, stream>>>(
        staged, counts, startpos, binbase, recs, offsets_row, flags,
        nb, n_nodes, chunk);
    // P0: x -> fp16 into the (now free) staged region
    const int n4 = (n_nodes * D) / 4;
    tohalf_kernel<<<2048, 256, 0, stream>>>(x, (__half2*)xh, n4);
    // K6: CSR SpMM, one wave per row, forced-ILP gathers
    spmm_csr_half_kernel<<<(n_nodes + 3) / 4, 256, 0, stream>>>(
        xh, offsets_row, binbase, recs, flags, out, n_nodes);
}